// Round 8
// baseline (372.634 us; speedup 1.0000x reference)
//
#include <hip/hip_runtime.h>
#include <hip/hip_bf16.h>

// SIREN + Fourier-features fused forward, MI355X (gfx950). Round 8.
// Barrier-free wave-dataflow: each wave owns 16 rows x ALL 256 neurons
// (acc[16] f32x4 = 64 regs). No __syncthreads anywhere. Layer handoff is
// within-wave: D-layout (lane&15=row) == B-operand n-layout, k regrouping
// done via a wave-PRIVATE 8KB LDS slab (write 16x b64, read 8x b128;
// compiler-ordered lgkmcnt, no cross-wave sharing). W re-packed kb-major
// (frag = kt*16 + jt) so each wave streams 128KB/layer sequentially ->
// L1 convoying across the 12 resident waves/CU. Fourier computed per-lane
// directly in B-fragment layout (no LDS, no exchange).

typedef __attribute__((ext_vector_type(8))) short bf16x8;
typedef __attribute__((ext_vector_type(4))) float f32x4;

#define NTOTAL 262144
#define HD 256
#define INV2PI 0.15915494309189535f

__device__ __forceinline__ unsigned short f2bf(float f) {
    unsigned int u = __float_as_uint(f);
    u += 0x7FFFu + ((u >> 16) & 1u);   // RNE (convert kernel only)
    return (unsigned short)(u >> 16);
}

// pack two floats -> 2xbf16 in one u32 (low = a, high = b), compiler-backed
__device__ __forceinline__ unsigned int pk2(float a, float b) {
    __hip_bfloat162 h = __float22bfloat162_rn(make_float2(a, b));
    union { __hip_bfloat162 h; unsigned int u; } c;
    c.h = h;
    return c.u;
}

__device__ __forceinline__ float sin_rev(float rev) {   // sin(2*pi*rev)
    return __builtin_amdgcn_sinf(__builtin_amdgcn_fractf(rev));
}

// ---------------- kernel 1: weight conversion + fragment packing ----------------
// wb (bf16 elems): 5 layers x 65536, each as 128 fragments x 512 elems,
// KB-MAJOR: fragidx = kt*16 + jt. Within fragment: elem (q*16+r)*8 + t for
// (j = jt*16 + r, k = kt*32 + q*8 + t). Then Wf row-major 16x256 zero-pad.
// Layer-0 weights pre-scaled by sqrt(2).
__global__ void convert_w(const float* __restrict__ W0, const float* __restrict__ Wh,
                          const float* __restrict__ Wf, unsigned short* __restrict__ wb) {
    const int i = blockIdx.x * 256 + threadIdx.x;      // grid 1280 -> 327680
    if (i < 327680) {
        const int l = i >> 16, rem = i & 65535;
        const int j = rem >> 8, k = rem & 255;
        const float v = (l == 0) ? W0[rem] * 1.41421356237309515f : Wh[i - 65536];
        const int jt = j >> 4, kt = k >> 5, q = (k >> 3) & 3, r = j & 15, t = k & 7;
        const int dst = (l << 16) + (((kt << 4) + jt) << 9) + (((q << 4) + r) << 3) + t;
        wb[dst] = f2bf(v);
    }
    if (i < 4096)
        wb[327680 + i] = (i < 512) ? f2bf(Wf[i]) : (unsigned short)0;
}

// ---------------- kernel 2: fused model, barrier-free ----------------
__global__ __launch_bounds__(256, 3) void siren_fused(
    const float* __restrict__ x, const float* __restrict__ scales,
    const float* __restrict__ Bm, const float* __restrict__ b0,
    const float* __restrict__ bh, const float* __restrict__ bfin,
    const unsigned short* __restrict__ wb, float* __restrict__ out) {

    __shared__ __align__(16) unsigned short A[4 * 16 * HD];   // 8KB private slab per wave

    const int tid  = threadIdx.x;
    const int lane = tid & 63;
    const int wid  = tid >> 6;
    const int arow = lane & 15;          // this lane's row within the wave's 16
    const int q    = lane >> 4;          // 0..3
    const int wrow0 = blockIdx.x * 64 + wid * 16;
    char* slab = (char*)A + wid * 8192;
    const int xr = (arow & 7) << 4;      // XOR swizzle bits
    const int rb = arow * 512;           // row byte base (16 rows x 512B)

    // ---- prefetch layer-0 unit-0 W fragments (before any compute) ----
    bf16x8 wfb[2][4];
    #pragma unroll
    for (int jj = 0; jj < 4; ++jj)
        wfb[0][jj] = *(const bf16x8*)(wb + (jj << 9) + lane * 8);

    // ---- Fourier features, computed directly in B-fragment layout ----
    // lane (arow,q) needs h[j'] for j' = kb*32 + q*8 + t; kb<4 -> sin(c), c=j';
    // kb>=4 -> cos(c), c=j'-128. c-set = {m*32 + q*8 + t}. sqrt2 folded into W0.
    bf16x8 hb[8];
    {
        const float* xrow = x + (wrow0 + arow) * 3;
        const float x0 = xrow[0] * scales[0] * INV2PI;
        const float x1 = xrow[1] * scales[1] * INV2PI;
        const float x2 = xrow[2] * scales[2] * INV2PI;
        #pragma unroll
        for (int m = 0; m < 4; ++m) {
            float sv[8], cv[8];
            #pragma unroll
            for (int t = 0; t < 8; ++t) {
                const int c = m * 32 + q * 8 + t;
                const float rev = x0 * Bm[c] + x1 * Bm[128 + c] + x2 * Bm[256 + c];
                const float fr  = __builtin_amdgcn_fractf(rev);
                sv[t] = __builtin_amdgcn_sinf(fr);
                cv[t] = __builtin_amdgcn_cosf(fr);
            }
            union { uint4 u; bf16x8 v; } cs, cc;
            cs.u.x = pk2(sv[0], sv[1]); cs.u.y = pk2(sv[2], sv[3]);
            cs.u.z = pk2(sv[4], sv[5]); cs.u.w = pk2(sv[6], sv[7]);
            cc.u.x = pk2(cv[0], cv[1]); cc.u.y = pk2(cv[2], cv[3]);
            cc.u.z = pk2(cv[4], cv[5]); cc.u.w = pk2(cv[6], cv[7]);
            hb[m]     = cs.v;
            hb[m + 4] = cc.v;
        }
    }

    // ---- 5 dense layers, no barriers ----
    #pragma unroll 1
    for (int layer = 0; layer < 5; ++layer) {
        const unsigned short* Wl = wb + (layer << 16);

        f32x4 acc[16];
        #pragma unroll
        for (int a = 0; a < 16; ++a) acc[a] = (f32x4)(0.0f);

        // 32 units: unit u = (kb = u>>2, jg = u&3), 4 MFMAs each, frags streamed
        // sequentially (kb-major layout). Ping-pong prefetch distance 1 unit.
        #pragma unroll
        for (int u = 0; u < 32; ++u) {
            const int kb = u >> 2, jg = u & 3;
            const int cur = u & 1, nxt = cur ^ 1;
            if (u < 31) {
                const int frag1 = (u + 1) << 2;   // (kb1*16 + jg1*4) == (u+1)*4
                #pragma unroll
                for (int jj = 0; jj < 4; ++jj)
                    wfb[nxt][jj] = *(const bf16x8*)(Wl + ((frag1 + jj) << 9) + lane * 8);
            }
            #pragma unroll
            for (int jj = 0; jj < 4; ++jj)
                acc[jg * 4 + jj] = __builtin_amdgcn_mfma_f32_16x16x32_bf16(
                    wfb[cur][jj], hb[kb], acc[jg * 4 + jj], 0, 0, 0);
        }

        // prefetch next layer's unit-0 W fragments (overlaps epilogue)
        if (layer < 4) {
            const unsigned short* Wn = wb + ((layer + 1) << 16);
            #pragma unroll
            for (int jj = 0; jj < 4; ++jj)
                wfb[0][jj] = *(const bf16x8*)(Wn + (jj << 9) + lane * 8);
        }

        // epilogue: sin(2*pi*(acc*s + b*s)), pack bf16, write to PRIVATE slab
        const float s = (layer == 0) ? (30.0f * INV2PI) : INV2PI;
        const float* bias = (layer == 0) ? b0 : (bh + (layer - 1) * HD);
        #pragma unroll
        for (int jt = 0; jt < 16; ++jt) {
            float4 bv = *(const float4*)(bias + jt * 16 + q * 4);
            const float e0 = sin_rev(fmaf(acc[jt][0], s, bv.x * s));
            const float e1 = sin_rev(fmaf(acc[jt][1], s, bv.y * s));
            const float e2 = sin_rev(fmaf(acc[jt][2], s, bv.z * s));
            const float e3 = sin_rev(fmaf(acc[jt][3], s, bv.w * s));
            uint2 val;
            val.x = pk2(e0, e1);
            val.y = pk2(e2, e3);
            *(uint2*)(slab + rb + ((jt * 32 + q * 8) ^ xr)) = val;
        }

        // within-wave layout transform: read back as B fragments (lgkmcnt-ordered)
        #pragma unroll
        for (int kb = 0; kb < 8; ++kb)
            hb[kb] = *(const bf16x8*)(slab + rb + ((kb * 64 + q * 16) ^ xr));
    }

    // ---- final linear 256 -> 2 (Wf zero-padded 16x256, row-major) ----
    {
        const unsigned short* Wfp = wb + 327680;
        f32x4 accf = (f32x4)(0.0f);
        #pragma unroll
        for (int kt = 0; kt < 8; ++kt) {
            const bf16x8 ff = *(const bf16x8*)(Wfp + arow * HD + kt * 32 + q * 8);
            accf = __builtin_amdgcn_mfma_f32_16x16x32_bf16(ff, hb[kt], accf, 0, 0, 0);
        }
        if (q == 0) {   // D: m = q*4+reg -> outputs 0,1 live in lanes q==0, reg 0,1
            float2 o;
            o.x = accf[0] + bfin[0];
            o.y = accf[1] + bfin[1];
            *(float2*)(out + (wrow0 + arow) * 2) = o;
        }
    }
}

extern "C" void kernel_launch(void* const* d_in, const int* in_sizes, int n_in,
                              void* d_out, int out_size, void* d_ws, size_t ws_size,
                              hipStream_t stream) {
    (void)in_sizes; (void)n_in; (void)out_size; (void)ws_size;
    const float* x      = (const float*)d_in[0];
    const float* scales = (const float*)d_in[1];
    const float* Bm     = (const float*)d_in[2];
    const float* W0     = (const float*)d_in[3];
    const float* b0     = (const float*)d_in[4];
    const float* Wh     = (const float*)d_in[5];
    const float* bh     = (const float*)d_in[6];
    const float* Wf     = (const float*)d_in[7];
    const float* bf     = (const float*)d_in[8];
    unsigned short* wb  = (unsigned short*)d_ws;   // needs 663552 B

    hipLaunchKernelGGL(convert_w, dim3(1280), dim3(256), 0, stream, W0, Wh, Wf, wb);
    hipLaunchKernelGGL(siren_fused, dim3(NTOTAL / 64), dim3(256), 0, stream,
                       x, scales, Bm, b0, bh, bf, wb, (float*)d_out);
}

// Round 9
// 200.842 us; speedup vs baseline: 1.8554x; 1.8554x over previous
//
#include <hip/hip_runtime.h>
#include <hip/hip_bf16.h>

// SIREN + Fourier-features fused forward, MI355X (gfx950). Round 9.
// = round 6 (203us best) + W-prefetch depth 2 (wfbuf[3][4], prefetch kt+2).
// Round-8 lesson: per-wave W traffic is the L2 budget -> keep the 4-wave
// neuron-quarter partition (32KB/wave/layer). Round-5 lesson: watch
// WRITE_SIZE for spills (est. regs ~164 vs (256,3) cap 170).

typedef __attribute__((ext_vector_type(8))) short bf16x8;
typedef __attribute__((ext_vector_type(4))) float f32x4;

#define NTOTAL 262144
#define BM 64
#define HD 256
#define INV2PI 0.15915494309189535f

__device__ __forceinline__ unsigned short f2bf(float f) {
    unsigned int u = __float_as_uint(f);
    u += 0x7FFFu + ((u >> 16) & 1u);   // RNE (convert kernel only)
    return (unsigned short)(u >> 16);
}

// pack two floats -> 2xbf16 in one u32 (low = a, high = b), compiler-backed
__device__ __forceinline__ unsigned int pk2(float a, float b) {
    __hip_bfloat162 h = __float22bfloat162_rn(make_float2(a, b));
    union { __hip_bfloat162 h; unsigned int u; } c;
    c.h = h;
    return c.u;
}

__device__ __forceinline__ float sin_rev(float rev) {   // sin(2*pi*rev)
    return __builtin_amdgcn_sinf(__builtin_amdgcn_fractf(rev));
}

// swizzled byte offset into the [64][256] bf16 LDS tile (row stride 512B)
__device__ __forceinline__ int a_off(int r, int byte) {
    return r * 512 + (byte ^ ((r & 7) << 4));
}

// ---------------- kernel 1: weight conversion + fragment packing ----------------
// wb layout (bf16 elems): 5 layers x 65536, each as 128 fragments x 512 elems.
// fragidx = jt_global*8 + kt; within-fragment elem = (q*16 + r)*8 + t, where
// j = jt_global*16 + r, k = kt*32 + q*8 + t. Then Wf row-major 16x256 zero-pad.
// Layer-0 weights pre-scaled by sqrt(2) (Fourier feature scale folded in).
__global__ void convert_w(const float* __restrict__ W0, const float* __restrict__ Wh,
                          const float* __restrict__ Wf, unsigned short* __restrict__ wb) {
    const int i = blockIdx.x * 256 + threadIdx.x;      // grid 1280 -> 327680
    if (i < 327680) {
        const int l = i >> 16, rem = i & 65535;
        const int j = rem >> 8, k = rem & 255;
        const float v = (l == 0) ? W0[rem] * 1.41421356237309515f : Wh[i - 65536];
        const int jt = j >> 4, kt = k >> 5, q = (k >> 3) & 3, r = j & 15, t = k & 7;
        const int dst = (l << 16) + (((jt << 3) + kt) << 9) + (((q << 4) + r) << 3) + t;
        wb[dst] = f2bf(v);
    }
    if (i < 4096)
        wb[327680 + i] = (i < 512) ? f2bf(Wf[i]) : (unsigned short)0;
}

// ---------------- kernel 2: fused model ----------------
__global__ __launch_bounds__(256, 3) void siren_fused(
    const float* __restrict__ x, const float* __restrict__ scales,
    const float* __restrict__ Bm, const float* __restrict__ b0,
    const float* __restrict__ bh, const float* __restrict__ bfin,
    const unsigned short* __restrict__ wb, float* __restrict__ out) {

    __shared__ __align__(16) unsigned short A[BM * HD];

    const int tid  = threadIdx.x;
    const int lane = tid & 63;
    const int wid  = tid >> 6;          // wave 0..3 owns neurons wid*64..+63
    const int row0 = blockIdx.x * BM;
    const int arow = lane & 15;
    const int q    = lane >> 4;         // 0..3
    const int kq   = q * 8;

    // ---- preload layer-0 kt=0 AND kt=1 W fragments (overlap Fourier stage) ----
    bf16x8 wfbuf[3][4];
    #pragma unroll
    for (int jt = 0; jt < 4; ++jt) {
        wfbuf[0][jt] = *(const bf16x8*)(wb + ((((wid * 4 + jt) << 3) + 0) << 9) + lane * 8);
        wfbuf[1][jt] = *(const bf16x8*)(wb + ((((wid * 4 + jt) << 3) + 1) << 9) + lane * 8);
    }

    // ---- Fourier feature stage (fp32; sqrt2 folded into W0) ----
    {
        const int r  = tid >> 2;            // 0..63
        const int c0 = (tid & 3) * 32;      // 32 freqs per thread
        const float* xr = x + (row0 + r) * 3;
        const float x0 = xr[0] * scales[0] * INV2PI;
        const float x1 = xr[1] * scales[1] * INV2PI;
        const float x2 = xr[2] * scales[2] * INV2PI;
        #pragma unroll
        for (int cc = 0; cc < 32; cc += 8) {
            const int c = c0 + cc;
            float sv[8], cv[8];
            #pragma unroll
            for (int t = 0; t < 8; ++t) {
                const float rev = x0 * Bm[c + t] + x1 * Bm[128 + c + t] + x2 * Bm[256 + c + t];
                const float fr  = __builtin_amdgcn_fractf(rev);
                sv[t] = __builtin_amdgcn_sinf(fr);
                cv[t] = __builtin_amdgcn_cosf(fr);
            }
            uint4 us, uc;
            us.x = pk2(sv[0], sv[1]); us.y = pk2(sv[2], sv[3]);
            us.z = pk2(sv[4], sv[5]); us.w = pk2(sv[6], sv[7]);
            uc.x = pk2(cv[0], cv[1]); uc.y = pk2(cv[2], cv[3]);
            uc.z = pk2(cv[4], cv[5]); uc.w = pk2(cv[6], cv[7]);
            *(uint4*)((char*)A + a_off(r, 2 * c))         = us;
            *(uint4*)((char*)A + a_off(r, 2 * (c + 128))) = uc;
        }
    }

    // ---- 5 dense layers ----
    #pragma unroll 1
    for (int layer = 0; layer < 5; ++layer) {
        const unsigned short* Wl = wb + (layer << 16);

        __syncthreads();   // h tile ready

        f32x4 acc[4][4];
        #pragma unroll
        for (int a = 0; a < 4; ++a)
            #pragma unroll
            for (int b = 0; b < 4; ++b)
                acc[a][b] = (f32x4)(0.0f);

        #pragma unroll
        for (int kt = 0; kt < 8; ++kt) {
            const int cur = kt % 3;
            // h fragments for this kt (LDS)
            bf16x8 hf[4];
            #pragma unroll
            for (int rt = 0; rt < 4; ++rt)
                hf[rt] = *(const bf16x8*)((const char*)A +
                    a_off(rt * 16 + arow, kt * 64 + q * 16));
            // W fragments for kt+2 (global; depth-2 ping-pong hides L2 latency)
            if (kt < 6) {
                const int nb = (kt + 2) % 3;
                #pragma unroll
                for (int jt = 0; jt < 4; ++jt)
                    wfbuf[nb][jt] = *(const bf16x8*)(Wl +
                        ((((wid * 4 + jt) << 3) + kt + 2) << 9) + lane * 8);
            }
            #pragma unroll
            for (int jt = 0; jt < 4; ++jt)
                #pragma unroll
                for (int rt = 0; rt < 4; ++rt)
                    acc[jt][rt] = __builtin_amdgcn_mfma_f32_16x16x32_bf16(
                        wfbuf[cur][jt], hf[rt], acc[jt][rt], 0, 0, 0);
        }

        __syncthreads();   // all reads of h done; safe to overwrite

        // prefetch next layer's kt=0,1 W fragments (overlaps epilogue)
        if (layer < 4) {
            const unsigned short* Wn = wb + ((layer + 1) << 16);
            #pragma unroll
            for (int jt = 0; jt < 4; ++jt) {
                wfbuf[0][jt] = *(const bf16x8*)(Wn + ((((wid * 4 + jt) << 3) + 0) << 9) + lane * 8);
                wfbuf[1][jt] = *(const bf16x8*)(Wn + ((((wid * 4 + jt) << 3) + 1) << 9) + lane * 8);
            }
        }

        // epilogue: sin(omega*(acc+b)) = sin(2*pi*(acc*s + b*s)),  s = omega/(2*pi)
        const float s = (layer == 0) ? (30.0f * INV2PI) : INV2PI;
        const float* bias = (layer == 0) ? b0 : (bh + (layer - 1) * HD);
        #pragma unroll
        for (int jt = 0; jt < 4; ++jt) {
            const int jj = wid * 64 + jt * 16 + q * 4;   // 4 consecutive neurons
            float4 bv = *(const float4*)(bias + jj);
            bv.x *= s; bv.y *= s; bv.z *= s; bv.w *= s;
            #pragma unroll
            for (int rt = 0; rt < 4; ++rt) {
                const int r = rt * 16 + arow;
                const float s0 = sin_rev(fmaf(acc[jt][rt][0], s, bv.x));
                const float s1 = sin_rev(fmaf(acc[jt][rt][1], s, bv.y));
                const float s2 = sin_rev(fmaf(acc[jt][rt][2], s, bv.z));
                const float s3 = sin_rev(fmaf(acc[jt][rt][3], s, bv.w));
                uint2 val;
                val.x = pk2(s0, s1);
                val.y = pk2(s2, s3);
                *(uint2*)((char*)A + a_off(r, jj * 2)) = val;
            }
        }
    }

    __syncthreads();   // final h ready

    // ---- final linear 256 -> 2, distributed: wave w handles rows w*16..+15 ----
    {
        const unsigned short* Wfp = wb + 327680;   // row-major [16][256], zero-padded
        f32x4 acc = (f32x4)(0.0f);
        #pragma unroll
        for (int kt = 0; kt < 8; ++kt) {
            const bf16x8 ff = *(const bf16x8*)(Wfp + arow * HD + kt * 32 + kq);
            const bf16x8 hf = *(const bf16x8*)((const char*)A +
                a_off(wid * 16 + arow, kt * 64 + q * 16));
            acc = __builtin_amdgcn_mfma_f32_16x16x32_bf16(ff, hf, acc, 0, 0, 0);
        }
        if (q == 0) {   // lanes 0-15 hold D rows j=0..3; j=0,1 are the two outputs
            const int rg = row0 + wid * 16 + arow;
            float2 o;
            o.x = acc[0] + bfin[0];
            o.y = acc[1] + bfin[1];
            *(float2*)(out + rg * 2) = o;
        }
    }
}

extern "C" void kernel_launch(void* const* d_in, const int* in_sizes, int n_in,
                              void* d_out, int out_size, void* d_ws, size_t ws_size,
                              hipStream_t stream) {
    (void)in_sizes; (void)n_in; (void)out_size; (void)ws_size;
    const float* x      = (const float*)d_in[0];
    const float* scales = (const float*)d_in[1];
    const float* Bm     = (const float*)d_in[2];
    const float* W0     = (const float*)d_in[3];
    const float* b0     = (const float*)d_in[4];
    const float* Wh     = (const float*)d_in[5];
    const float* bh     = (const float*)d_in[6];
    const float* Wf     = (const float*)d_in[7];
    const float* bf     = (const float*)d_in[8];
    unsigned short* wb  = (unsigned short*)d_ws;   // needs 663552 B

    hipLaunchKernelGGL(convert_w, dim3(1280), dim3(256), 0, stream, W0, Wh, Wf, wb);
    hipLaunchKernelGGL(siren_fused, dim3(NTOTAL / BM), dim3(256), 0, stream,
                       x, scales, Bm, b0, bh, bf, wb, (float*)d_out);
}